// Round 1
// baseline (194.899 us; speedup 1.0000x reference)
//
#include <hip/hip_runtime.h>

// Q6ArithmeticLayer: out = softmax(-hs * 3*(1 - dot(normalize(tanh(x@W^T)), normalize(P))), axis=-1)
// x: (B*T, 1024) fp32, W: (6, 1024), P: (8, 6), out: (B*T, 8) fp32.
// Memory-bound: stream x once (134 MB). One wave per token; W cached in VGPRs
// (96 regs/lane = 16 cols x 6 rows), amortized over a 4-token grid-stride loop.

#define DIM 1024
#define NK 6
#define NPROTO 8

__global__ __launch_bounds__(256, 2) void q6_fused_kernel(
    const float* __restrict__ x,
    const float* __restrict__ W,
    const float* __restrict__ protos,
    const float* __restrict__ hs_ptr,
    float* __restrict__ out,
    int n_tokens, int n_waves)
{
    const int lane = threadIdx.x & 63;
    const int wave_id = blockIdx.x * (blockDim.x >> 6) + (threadIdx.x >> 6);
    const int cbase = lane * 4;  // this lane's base column within each 256-col group

    // --- W fragment into registers: 6 rows x (4 x float4) = 96 VGPRs ---
    float4 wreg[NK][4];
#pragma unroll
    for (int k = 0; k < NK; ++k)
#pragma unroll
        for (int j = 0; j < 4; ++j)
            wreg[k][j] = *reinterpret_cast<const float4*>(&W[k * DIM + j * 256 + cbase]);

    // --- normalized prototype for this lane (lane & 7 selects the proto row) ---
    const int pl = lane & 7;
    float p0 = protos[pl * 6 + 0], p1 = protos[pl * 6 + 1], p2 = protos[pl * 6 + 2];
    float p3 = protos[pl * 6 + 3], p4 = protos[pl * 6 + 4], p5 = protos[pl * 6 + 5];
    {
        float pn = sqrtf(p0*p0 + p1*p1 + p2*p2 + p3*p3 + p4*p4 + p5*p5);
        float inv = 1.0f / fmaxf(pn, 1e-12f);
        p0 *= inv; p1 *= inv; p2 *= inv; p3 *= inv; p4 *= inv; p5 *= inv;
    }
    const float hs = hs_ptr[0];

    for (int t = wave_id; t < n_tokens; t += n_waves) {
        const float* xt = x + (size_t)t * DIM;
        float acc0 = 0.f, acc1 = 0.f, acc2 = 0.f, acc3 = 0.f, acc4 = 0.f, acc5 = 0.f;
#pragma unroll
        for (int j = 0; j < 4; ++j) {
            float4 xv = *reinterpret_cast<const float4*>(&xt[j * 256 + cbase]);
            acc0 = fmaf(xv.x, wreg[0][j].x, acc0); acc0 = fmaf(xv.y, wreg[0][j].y, acc0);
            acc0 = fmaf(xv.z, wreg[0][j].z, acc0); acc0 = fmaf(xv.w, wreg[0][j].w, acc0);
            acc1 = fmaf(xv.x, wreg[1][j].x, acc1); acc1 = fmaf(xv.y, wreg[1][j].y, acc1);
            acc1 = fmaf(xv.z, wreg[1][j].z, acc1); acc1 = fmaf(xv.w, wreg[1][j].w, acc1);
            acc2 = fmaf(xv.x, wreg[2][j].x, acc2); acc2 = fmaf(xv.y, wreg[2][j].y, acc2);
            acc2 = fmaf(xv.z, wreg[2][j].z, acc2); acc2 = fmaf(xv.w, wreg[2][j].w, acc2);
            acc3 = fmaf(xv.x, wreg[3][j].x, acc3); acc3 = fmaf(xv.y, wreg[3][j].y, acc3);
            acc3 = fmaf(xv.z, wreg[3][j].z, acc3); acc3 = fmaf(xv.w, wreg[3][j].w, acc3);
            acc4 = fmaf(xv.x, wreg[4][j].x, acc4); acc4 = fmaf(xv.y, wreg[4][j].y, acc4);
            acc4 = fmaf(xv.z, wreg[4][j].z, acc4); acc4 = fmaf(xv.w, wreg[4][j].w, acc4);
            acc5 = fmaf(xv.x, wreg[5][j].x, acc5); acc5 = fmaf(xv.y, wreg[5][j].y, acc5);
            acc5 = fmaf(xv.z, wreg[5][j].z, acc5); acc5 = fmaf(xv.w, wreg[5][j].w, acc5);
        }
        // butterfly reduction across the 64 lanes (all lanes end with full sums)
#pragma unroll
        for (int off = 32; off >= 1; off >>= 1) {
            acc0 += __shfl_xor(acc0, off, 64);
            acc1 += __shfl_xor(acc1, off, 64);
            acc2 += __shfl_xor(acc2, off, 64);
            acc3 += __shfl_xor(acc3, off, 64);
            acc4 += __shfl_xor(acc4, off, 64);
            acc5 += __shfl_xor(acc5, off, 64);
        }
        if (lane < NPROTO) {
            // tanh via hw exp2: tanh(a) = sign(a) * (1-e)/(1+e), e = exp(-2|a|)
            float z[NK];
            float a_in[NK] = {acc0, acc1, acc2, acc3, acc4, acc5};
#pragma unroll
            for (int k = 0; k < NK; ++k) {
                float a = a_in[k];
                float e = __expf(-2.0f * fabsf(a));
                float th = (1.0f - e) / (1.0f + e);
                z[k] = copysignf(th, a);
            }
            float nrm = sqrtf(z[0]*z[0] + z[1]*z[1] + z[2]*z[2] +
                              z[3]*z[3] + z[4]*z[4] + z[5]*z[5]);
            float inv = 1.0f / fmaxf(nrm, 1e-6f);
            float dot = (z[0]*p0 + z[1]*p1 + z[2]*p2 + z[3]*p3 + z[4]*p4 + z[5]*p5) * inv;
            float logit = -hs * (6.0f - dot * 6.0f) * 0.5f;
            // softmax across the 8 proto lanes (xor masks 1,2,4 stay within group)
            float m = logit;
            m = fmaxf(m, __shfl_xor(m, 1, 64));
            m = fmaxf(m, __shfl_xor(m, 2, 64));
            m = fmaxf(m, __shfl_xor(m, 4, 64));
            float e = __expf(logit - m);
            float s = e;
            s += __shfl_xor(s, 1, 64);
            s += __shfl_xor(s, 2, 64);
            s += __shfl_xor(s, 4, 64);
            out[(size_t)t * NPROTO + lane] = e / s;
        }
    }
}

extern "C" void kernel_launch(void* const* d_in, const int* in_sizes, int n_in,
                              void* d_out, int out_size, void* d_ws, size_t ws_size,
                              hipStream_t stream) {
    const float* x      = (const float*)d_in[0];
    const float* W      = (const float*)d_in[1];
    const float* protos = (const float*)d_in[2];
    const float* hs     = (const float*)d_in[3];
    float* out = (float*)d_out;

    const int n_tokens = in_sizes[0] / DIM;   // 32768
    const int blocks = 2048;                  // 8192 waves -> 4 tokens/wave
    const int threads = 256;
    const int n_waves = blocks * (threads / 64);

    q6_fused_kernel<<<blocks, threads, 0, stream>>>(
        x, W, protos, hs, out, n_tokens, n_waves);
}

// Round 2
// 192.100 us; speedup vs baseline: 1.0146x; 1.0146x over previous
//
#include <hip/hip_runtime.h>

// Q6ArithmeticLayer: out = softmax(-hs * 3*(1 - dot(normalize(tanh(x@W^T)), normalize(P))))
// x: (32768, 1024) fp32 -> 134 MB stream (the roofline, ~21 us @ 6.3 TB/s).
// R2: 4 tokens per wave iteration + reduce-scatter/group-butterfly reduction.
//   - 64 lanes each load 16B x 4 (j) x 4 tokens -> 16 dwordx4 in flight.
//   - reduction: xor32 token-pair scatter (12 shfl) + xor16 (6 shfl) leaves
//     token t in 16-lane group t; xor{8,4,2,1} butterfly (24 shfl) gives all
//     group lanes the full 6 sums. 42 shfls / 4 tokens vs 144 naive.
//   - epilogue: lanes (group*16 + p), p<8 -> proto p of token group; all 4
//     softmax chains share one instruction stream.

#define DIM 1024
#define NK 6
#define NPROTO 8
#define TPI 4  // tokens per wave iteration

__global__ __launch_bounds__(256, 2) void q6_fused_kernel(
    const float* __restrict__ x,
    const float* __restrict__ W,
    const float* __restrict__ protos,
    const float* __restrict__ hs_ptr,
    float* __restrict__ out,
    int n_tokens, int n_waves)
{
    const int lane = threadIdx.x & 63;
    const int wave_id = blockIdx.x * (blockDim.x >> 6) + (threadIdx.x >> 6);
    const int cbase = lane * 4;  // this lane's base column within each 256-col group

    // --- W fragment in registers: 6 rows x 4 x float4 = 96 VGPRs (L2-resident load) ---
    float4 wreg[NK][4];
#pragma unroll
    for (int k = 0; k < NK; ++k)
#pragma unroll
        for (int j = 0; j < 4; ++j)
            wreg[k][j] = *reinterpret_cast<const float4*>(&W[k * DIM + j * 256 + cbase]);

    // --- normalized prototype for this lane's proto slot ---
    const int pl = lane & 7;
    float p[NK];
#pragma unroll
    for (int k = 0; k < NK; ++k) p[k] = protos[pl * NK + k];
    {
        float pn = sqrtf(p[0]*p[0] + p[1]*p[1] + p[2]*p[2] + p[3]*p[3] + p[4]*p[4] + p[5]*p[5]);
        float inv = 1.0f / fmaxf(pn, 1e-12f);
#pragma unroll
        for (int k = 0; k < NK; ++k) p[k] *= inv;
    }
    const float hs = hs_ptr[0];

    const bool hi5 = (lane & 32) != 0;
    const bool hi4 = (lane & 16) != 0;
    const int tloc = lane >> 4;   // which of the 4 tokens this 16-lane group owns
    const int pidx = lane & 15;   // proto slot within the group (active if <8)

    for (int tb = wave_id * TPI; tb < n_tokens; tb += n_waves * TPI) {
        // ---- load x for 4 tokens: 16 x global_load_dwordx4, all in flight ----
        float4 xv[TPI][4];
#pragma unroll
        for (int t = 0; t < TPI; ++t) {
            const float* xt = x + (size_t)(tb + t) * DIM;
#pragma unroll
            for (int j = 0; j < 4; ++j)
                xv[t][j] = *reinterpret_cast<const float4*>(&xt[j * 256 + cbase]);
        }

        // ---- 24 accumulators: acc[t][k] = partial dot over this lane's 16 cols ----
        float acc[TPI][NK];
#pragma unroll
        for (int t = 0; t < TPI; ++t)
#pragma unroll
            for (int k = 0; k < NK; ++k) acc[t][k] = 0.0f;
#pragma unroll
        for (int t = 0; t < TPI; ++t)
#pragma unroll
            for (int j = 0; j < 4; ++j) {
                const float4 xvj = xv[t][j];
#pragma unroll
                for (int k = 0; k < NK; ++k) {
                    float a = acc[t][k];
                    a = fmaf(xvj.x, wreg[k][j].x, a);
                    a = fmaf(xvj.y, wreg[k][j].y, a);
                    a = fmaf(xvj.z, wreg[k][j].z, a);
                    a = fmaf(xvj.w, wreg[k][j].w, a);
                    acc[t][k] = a;
                }
            }

        // ---- step 1: xor 32 — token-pair reduce-scatter (12 shfl) ----
        // after: bit5=0 lanes hold tokens {0,1}, bit5=1 lanes hold {2,3}
        float r[2][NK];
#pragma unroll
        for (int tp = 0; tp < 2; ++tp)
#pragma unroll
            for (int k = 0; k < NK; ++k) {
                float send = hi5 ? acc[tp][k]     : acc[2 + tp][k];
                float keep = hi5 ? acc[2 + tp][k] : acc[tp][k];
                r[tp][k] = keep + __shfl_xor(send, 32, 64);
            }

        // ---- step 2: xor 16 — token reduce-scatter (6 shfl) ----
        // after: 16-lane group g owns token g (sum over lanes {L, L^16, L^32, L^48})
        float z[NK];
#pragma unroll
        for (int k = 0; k < NK; ++k) {
            float send = hi4 ? r[0][k] : r[1][k];
            float keep = hi4 ? r[1][k] : r[0][k];
            z[k] = keep + __shfl_xor(send, 16, 64);
        }

        // ---- steps 3-6: butterfly within the 16-lane group (24 shfl) ----
#pragma unroll
        for (int off = 8; off >= 1; off >>= 1)
#pragma unroll
            for (int k = 0; k < NK; ++k)
                z[k] += __shfl_xor(z[k], off, 64);

        // ---- epilogue: lanes p<8 of each group handle proto p of token tloc ----
        if (pidx < NPROTO) {
            float zz[NK];
            float nrm2 = 0.0f;
#pragma unroll
            for (int k = 0; k < NK; ++k) {
                float a = z[k];
                // tanh(a) = sign(a) * (1-e)/(1+e), e = exp(-2|a|) — hw v_exp_f32
                float e = __expf(-2.0f * fabsf(a));
                float th = (1.0f - e) / (1.0f + e);
                zz[k] = copysignf(th, a);
                nrm2 = fmaf(zz[k], zz[k], nrm2);
            }
            float inv = 1.0f / fmaxf(sqrtf(nrm2), 1e-6f);
            float dot = (zz[0]*p[0] + zz[1]*p[1] + zz[2]*p[2] +
                         zz[3]*p[3] + zz[4]*p[4] + zz[5]*p[5]) * inv;
            float logit = -hs * (6.0f - dot * 6.0f) * 0.5f;
            // softmax over the 8 proto lanes (xor 1,2,4 stays in the subgroup)
            float m = logit;
            m = fmaxf(m, __shfl_xor(m, 1, 64));
            m = fmaxf(m, __shfl_xor(m, 2, 64));
            m = fmaxf(m, __shfl_xor(m, 4, 64));
            float e = __expf(logit - m);
            float s = e;
            s += __shfl_xor(s, 1, 64);
            s += __shfl_xor(s, 2, 64);
            s += __shfl_xor(s, 4, 64);
            out[(size_t)(tb + tloc) * NPROTO + pidx] = e / s;
        }
    }
}

extern "C" void kernel_launch(void* const* d_in, const int* in_sizes, int n_in,
                              void* d_out, int out_size, void* d_ws, size_t ws_size,
                              hipStream_t stream) {
    const float* x      = (const float*)d_in[0];
    const float* W      = (const float*)d_in[1];
    const float* protos = (const float*)d_in[2];
    const float* hs     = (const float*)d_in[3];
    float* out = (float*)d_out;

    const int n_tokens = in_sizes[0] / DIM;   // 32768
    const int blocks = 2048;                  // 8192 waves x 4 tokens = 32768, one pass
    const int threads = 256;
    const int n_waves = blocks * (threads / 64);

    q6_fused_kernel<<<blocks, threads, 0, stream>>>(
        x, W, protos, hs, out, n_tokens, n_waves);
}